// Round 4
// baseline (94.122 us; speedup 1.0000x reference)
//
#include <hip/hip_runtime.h>
#include <hip/hip_cooperative_groups.h>

namespace cg = cooperative_groups;

#define HH 1024
#define WW 1024
#define NA 64
#define NBLK 1024   // one row per block

// ws layout: float2 partials[NBLK]  (x = sum field^2, y = sum upd^2)

__global__ __launch_bounds__(256) void frp_coop(
    const float4* __restrict__ field,
    const float4* __restrict__ signal,
    const int*   __restrict__ apos,       // [NA][2]
    const float* __restrict__ astr,       // [NA]
    const float* __restrict__ p_is,
    const float* __restrict__ p_gr,
    const float* __restrict__ p_lr,
    float4* __restrict__ out,
    float2* __restrict__ part)
{
    __shared__ int   s_pj[NA];
    __shared__ int   s_rad[NA];
    __shared__ int   s_di2[NA];
    __shared__ float s_coef[NA];
    __shared__ float s_inv[NA];
    __shared__ int   s_nact;
    __shared__ float s_part[2][4];
    __shared__ float s_scale;

    const float lr = *p_lr;
    const float gr = *p_gr;
    const float is = *p_is;

    const int row = blockIdx.x;
    const int t   = threadIdx.x;

    // ---- wave 0: compact row-active attractors (~1.1 of 64 on average) ----
    if (t < NA) {
        float s  = astr[t];
        int   pi = apos[2 * t + 0];
        int   pj = apos[2 * t + 1];
        int   r  = (int)floorf(5.0f * s);
        int   di = row - pi;
        bool active = (di >= -r && di <= r);
        unsigned long long mask = __ballot(active);
        int pos = __popcll(mask & ((1ull << t) - 1ull));
        if (active) {
            s_pj[pos]   = pj;
            s_rad[pos]  = r;
            s_di2[pos]  = di * di;
            s_coef[pos] = lr * s;
            s_inv[pos]  = -0.125f / (s * s);   // = -0.5 / (4 s^2)
        }
        if (t == 0) s_nact = __popcll(mask);
    }
    __syncthreads();

    // ---- phase A: influence + blend, result held in registers ----
    const int col0 = t << 2;
    const int n    = s_nact;

    float c0 = 0.f, c1 = 0.f, c2 = 0.f, c3 = 0.f;
    for (int k = 0; k < n; ++k) {
        int   pj  = s_pj[k];              // broadcast LDS reads
        int   r   = s_rad[k];
        int   di2 = s_di2[k];
        float cf  = s_coef[k];
        float iv  = s_inv[k];
        int dj = col0 - pj;
        if (dj >= -r && dj <= r) c0 += cf * __expf(iv * (float)(di2 + dj * dj));
        int d1 = dj + 1;
        if (d1 >= -r && d1 <= r) c1 += cf * __expf(iv * (float)(di2 + d1 * d1));
        int d2 = dj + 2;
        if (d2 >= -r && d2 <= r) c2 += cf * __expf(iv * (float)(di2 + d2 * d2));
        int d3 = dj + 3;
        if (d3 >= -r && d3 <= r) c3 += cf * __expf(iv * (float)(di2 + d3 * d3));
    }

    const int idx = row * (WW / 4) + t;
    float4 f  = field[idx];
    float4 sg = signal[idx];

    float a0 = is / (1.0f + expf(-(gr + c0)));
    float a1 = is / (1.0f + expf(-(gr + c1)));
    float a2 = is / (1.0f + expf(-(gr + c2)));
    float a3 = is / (1.0f + expf(-(gr + c3)));

    float4 u;
    u.x = f.x + (sg.x - f.x) * a0;
    u.y = f.y + (sg.y - f.y) * a1;
    u.z = f.z + (sg.z - f.z) * a2;
    u.w = f.w + (sg.w - f.w) * a3;

    // per-block partial sums
    float sf = f.x * f.x + f.y * f.y + f.z * f.z + f.w * f.w;
    float su = u.x * u.x + u.y * u.y + u.z * u.z + u.w * u.w;
#pragma unroll
    for (int off = 32; off > 0; off >>= 1) {
        sf += __shfl_down(sf, off, 64);
        su += __shfl_down(su, off, 64);
    }
    const int wave = t >> 6;
    if ((t & 63) == 0) {
        s_part[0][wave] = sf;
        s_part[1][wave] = su;
    }
    __syncthreads();
    if (t == 0) {
        float tf = s_part[0][0] + s_part[0][1] + s_part[0][2] + s_part[0][3];
        float tu = s_part[1][0] + s_part[1][1] + s_part[1][2] + s_part[1][3];
        part[blockIdx.x] = make_float2(tf, tu);
        __threadfence();                 // device-scope release of the partial
    }

    // ---- grid-wide barrier ----
    cg::this_grid().sync();

    // ---- phase B: every block reduces the 1024 float2 partials (8 KB) ----
    const float4* p4 = (const float4*)part;   // (f_{2k}, u_{2k}, f_{2k+1}, u_{2k+1})
    float4 v0 = p4[t];
    float4 v1 = p4[t + 256];
    double df = (double)v0.x + (double)v0.z + (double)v1.x + (double)v1.z;
    double du = (double)v0.y + (double)v0.w + (double)v1.y + (double)v1.w;
#pragma unroll
    for (int off = 32; off > 0; off >>= 1) {
        df += __shfl_down(df, off, 64);
        du += __shfl_down(du, off, 64);
    }
    __syncthreads();                     // s_part reuse hazard guard
    if ((t & 63) == 0) {
        s_part[0][wave] = (float)df;     // store per-wave sums (fits float fine)
        s_part[1][wave] = (float)du;
    }
    __syncthreads();
    if (t == 0) {
        double tf = (double)s_part[0][0] + (double)s_part[0][1]
                  + (double)s_part[0][2] + (double)s_part[0][3];
        double tu = (double)s_part[1][0] + (double)s_part[1][1]
                  + (double)s_part[1][2] + (double)s_part[1][3];
        s_scale = (tu > 0.0) ? (float)sqrt(tf / tu) : 1.0f;
    }
    __syncthreads();

    const float sc = s_scale;
    u.x *= sc; u.y *= sc; u.z *= sc; u.w *= sc;
    out[idx] = u;
}

extern "C" void kernel_launch(void* const* d_in, const int* in_sizes, int n_in,
                              void* d_out, int out_size, void* d_ws, size_t ws_size,
                              hipStream_t stream) {
    const float4* field  = (const float4*)d_in[0];
    const float4* signal = (const float4*)d_in[1];
    const int*    apos   = (const int*)d_in[2];
    const float*  astr   = (const float*)d_in[3];
    const float*  p_is   = (const float*)d_in[4];
    const float*  p_gr   = (const float*)d_in[5];
    const float*  p_lr   = (const float*)d_in[6];
    float4*       out    = (float4*)d_out;
    float2*       part   = (float2*)d_ws;

    void* args[] = { (void*)&field, (void*)&signal, (void*)&apos, (void*)&astr,
                     (void*)&p_is, (void*)&p_gr, (void*)&p_lr,
                     (void*)&out, (void*)&part };

    hipLaunchCooperativeKernel((void*)frp_coop, dim3(NBLK), dim3(256),
                               args, 0, stream);
}

// Round 5
// 84.885 us; speedup vs baseline: 1.1088x; 1.1088x over previous
//
#include <hip/hip_runtime.h>

#define HH 1024
#define WW 1024
#define NA 64
#define NBLK 1024
#define NGRP 32            // 32 groups x 32 blocks

// ws layout (bytes):
//   [0]            uint flag: 0 = not ready, else float bits of scale (>0)
//   [128]          int  root counter
//   [256 + g*128]  int  group counter g  (g < NGRP)   — each on its own line
//   [4352]         float2 part[NBLK]
#define WS_ZERO_BYTES 4352

__global__ __launch_bounds__(256) void frp_one(
    const float4* __restrict__ field,
    const float4* __restrict__ signal,
    const int*   __restrict__ apos,       // [NA][2]
    const float* __restrict__ astr,       // [NA]
    const float* __restrict__ p_is,
    const float* __restrict__ p_gr,
    const float* __restrict__ p_lr,
    float4* __restrict__ out,
    int*    __restrict__ wsi,             // counters/flag
    float2* __restrict__ part)
{
    __shared__ int   s_pj[NA];
    __shared__ int   s_rad[NA];
    __shared__ int   s_di2[NA];
    __shared__ float s_coef[NA];
    __shared__ float s_inv[NA];
    __shared__ int   s_nact;
    __shared__ float s_partA[2][4];
    __shared__ double s_partB[2][4];
    __shared__ int   s_last;
    __shared__ unsigned s_bits;

    const float lr = *p_lr;
    const float gr = *p_gr;
    const float is = *p_is;

    const int row = blockIdx.x;
    const int t   = threadIdx.x;

    // ---- wave 0: compact row-active attractors (~1.1 of 64 on average) ----
    if (t < NA) {
        float s  = astr[t];
        int   pi = apos[2 * t + 0];
        int   pj = apos[2 * t + 1];
        int   r  = (int)floorf(5.0f * s);
        int   di = row - pi;
        bool active = (di >= -r && di <= r);
        unsigned long long mask = __ballot(active);
        int pos = __popcll(mask & ((1ull << t) - 1ull));
        if (active) {
            s_pj[pos]   = pj;
            s_rad[pos]  = r;
            s_di2[pos]  = di * di;
            s_coef[pos] = lr * s;
            s_inv[pos]  = -0.125f / (s * s);   // = -0.5 / (4 s^2)
        }
        if (t == 0) s_nact = __popcll(mask);
    }
    __syncthreads();

    // ---- phase A: influence + blend, result held in registers ----
    const int col0 = t << 2;
    const int n    = s_nact;

    float c0 = 0.f, c1 = 0.f, c2 = 0.f, c3 = 0.f;
    for (int k = 0; k < n; ++k) {
        int   pj  = s_pj[k];              // broadcast LDS reads
        int   r   = s_rad[k];
        int   di2 = s_di2[k];
        float cf  = s_coef[k];
        float iv  = s_inv[k];
        int dj = col0 - pj;
        if (dj >= -r && dj <= r) c0 += cf * __expf(iv * (float)(di2 + dj * dj));
        int d1 = dj + 1;
        if (d1 >= -r && d1 <= r) c1 += cf * __expf(iv * (float)(di2 + d1 * d1));
        int d2 = dj + 2;
        if (d2 >= -r && d2 <= r) c2 += cf * __expf(iv * (float)(di2 + d2 * d2));
        int d3 = dj + 3;
        if (d3 >= -r && d3 <= r) c3 += cf * __expf(iv * (float)(di2 + d3 * d3));
    }

    const int idx = row * (WW / 4) + t;
    float4 f  = field[idx];
    float4 sg = signal[idx];

    float a0 = is / (1.0f + __expf(-(gr + c0)));
    float a1 = is / (1.0f + __expf(-(gr + c1)));
    float a2 = is / (1.0f + __expf(-(gr + c2)));
    float a3 = is / (1.0f + __expf(-(gr + c3)));

    float4 u;
    u.x = f.x + (sg.x - f.x) * a0;
    u.y = f.y + (sg.y - f.y) * a1;
    u.z = f.z + (sg.z - f.z) * a2;
    u.w = f.w + (sg.w - f.w) * a3;

    // per-block partial sums
    float sf = f.x * f.x + f.y * f.y + f.z * f.z + f.w * f.w;
    float su = u.x * u.x + u.y * u.y + u.z * u.z + u.w * u.w;
#pragma unroll
    for (int off = 32; off > 0; off >>= 1) {
        sf += __shfl_down(sf, off, 64);
        su += __shfl_down(su, off, 64);
    }
    const int wave = t >> 6;
    if ((t & 63) == 0) {
        s_partA[0][wave] = sf;
        s_partA[1][wave] = su;
    }
    __syncthreads();

    // ---- arrival: publish partial, 2-level tree counter ----
    if (t == 0) {
        float tf = s_partA[0][0] + s_partA[0][1] + s_partA[0][2] + s_partA[0][3];
        float tu = s_partA[1][0] + s_partA[1][1] + s_partA[1][2] + s_partA[1][3];
        part[row] = make_float2(tf, tu);
        __threadfence();                               // release partial device-wide
        int g = row & (NGRP - 1);
        int old = atomicAdd(&wsi[64 + 32 * g], 1);     // group counter (own line)
        int last = 0;
        if (old == NGRP - 1) {                         // group leader
            int o2 = atomicAdd(&wsi[32], 1);           // root
            if (o2 == NGRP - 1) last = 1;              // last block overall
        }
        s_last = last;
    }
    __syncthreads();

    // ---- last block: reduce 1024 partials, publish scale in flag ----
    if (s_last) {
        __threadfence();                               // acquire: invalidate caches
        const float4* p4 = (const float4*)part;        // (f0,u0,f1,u1) pairs
        float4 v0 = p4[t];
        float4 v1 = p4[t + 256];
        double df = (double)v0.x + (double)v0.z + (double)v1.x + (double)v1.z;
        double du = (double)v0.y + (double)v0.w + (double)v1.y + (double)v1.w;
#pragma unroll
        for (int off = 32; off > 0; off >>= 1) {
            df += __shfl_down(df, off, 64);
            du += __shfl_down(du, off, 64);
        }
        if ((t & 63) == 0) { s_partB[0][wave] = df; s_partB[1][wave] = du; }
        __syncthreads();
        if (t == 0) {
            double tf = s_partB[0][0] + s_partB[0][1] + s_partB[0][2] + s_partB[0][3];
            double tu = s_partB[1][0] + s_partB[1][1] + s_partB[1][2] + s_partB[1][3];
            float scale = (tu > 0.0) ? (float)sqrt(tf / tu) : 1.0f;
            __hip_atomic_store((unsigned*)&wsi[0], __float_as_uint(scale),
                               __ATOMIC_RELEASE, __HIP_MEMORY_SCOPE_AGENT);
        }
    }

    // ---- everyone: spin for the scale (last block sails through) ----
    if (t == 0) {
        unsigned v;
        while ((v = __hip_atomic_load((const unsigned*)&wsi[0],
                                      __ATOMIC_ACQUIRE, __HIP_MEMORY_SCOPE_AGENT)) == 0u)
            __builtin_amdgcn_s_sleep(2);
        s_bits = v;
    }
    __syncthreads();

    const float sc = __uint_as_float(s_bits);
    u.x *= sc; u.y *= sc; u.z *= sc; u.w *= sc;
    out[idx] = u;
}

extern "C" void kernel_launch(void* const* d_in, const int* in_sizes, int n_in,
                              void* d_out, int out_size, void* d_ws, size_t ws_size,
                              hipStream_t stream) {
    const float4* field  = (const float4*)d_in[0];
    const float4* signal = (const float4*)d_in[1];
    const int*    apos   = (const int*)d_in[2];
    const float*  astr   = (const float*)d_in[3];
    const float*  p_is   = (const float*)d_in[4];
    const float*  p_gr   = (const float*)d_in[5];
    const float*  p_lr   = (const float*)d_in[6];

    int*    wsi  = (int*)d_ws;
    float2* part = (float2*)((char*)d_ws + WS_ZERO_BYTES);

    hipMemsetAsync(d_ws, 0, WS_ZERO_BYTES, stream);    // reset flag + counters

    frp_one<<<NBLK, 256, 0, stream>>>(
        field, signal, apos, astr, p_is, p_gr, p_lr,
        (float4*)d_out, wsi, part);
}

// Round 6
// 14.576 us; speedup vs baseline: 6.4573x; 5.8235x over previous
//
#include <hip/hip_runtime.h>

#define HH 1024
#define WW 1024
#define NA 64
#define NBLK 1024

// ws layout: float2 part[NBLK]  (x = sum field^2, y = sum upd^2)

// ---------------- Kernel 1: norm partials only (no out write) ---------------
__global__ __launch_bounds__(256) void frp_norm(
    const float4* __restrict__ field,
    const float4* __restrict__ signal,
    const int*   __restrict__ apos,       // [NA][2]
    const float* __restrict__ astr,       // [NA]
    const float* __restrict__ p_is,
    const float* __restrict__ p_gr,
    const float* __restrict__ p_lr,
    float2* __restrict__ part)
{
    __shared__ int   s_pj[NA];
    __shared__ int   s_rad[NA];
    __shared__ int   s_di2[NA];
    __shared__ float s_coef[NA];
    __shared__ float s_inv[NA];
    __shared__ int   s_nact;
    __shared__ float s_part[2][4];

    const float lr = *p_lr;
    const float gr = *p_gr;
    const float is = *p_is;

    const int row = blockIdx.x;
    const int t   = threadIdx.x;

    if (t < NA) {                         // wave 0: compact row-active attractors
        float s  = astr[t];
        int   pi = apos[2 * t + 0];
        int   pj = apos[2 * t + 1];
        int   r  = (int)floorf(5.0f * s);
        int   di = row - pi;
        bool active = (di >= -r && di <= r);
        unsigned long long mask = __ballot(active);
        int pos = __popcll(mask & ((1ull << t) - 1ull));
        if (active) {
            s_pj[pos]   = pj;
            s_rad[pos]  = r;
            s_di2[pos]  = di * di;
            s_coef[pos] = lr * s;
            s_inv[pos]  = -0.125f / (s * s);
        }
        if (t == 0) s_nact = __popcll(mask);
    }
    __syncthreads();

    const int col0 = t << 2;
    const int n    = s_nact;

    float c0 = 0.f, c1 = 0.f, c2 = 0.f, c3 = 0.f;
    for (int k = 0; k < n; ++k) {
        int   pj  = s_pj[k];
        int   r   = s_rad[k];
        int   di2 = s_di2[k];
        float cf  = s_coef[k];
        float iv  = s_inv[k];
        int dj = col0 - pj;
        if (dj >= -r && dj <= r) c0 += cf * __expf(iv * (float)(di2 + dj * dj));
        int d1 = dj + 1;
        if (d1 >= -r && d1 <= r) c1 += cf * __expf(iv * (float)(di2 + d1 * d1));
        int d2 = dj + 2;
        if (d2 >= -r && d2 <= r) c2 += cf * __expf(iv * (float)(di2 + d2 * d2));
        int d3 = dj + 3;
        if (d3 >= -r && d3 <= r) c3 += cf * __expf(iv * (float)(di2 + d3 * d3));
    }

    const int idx = row * (WW / 4) + t;
    float4 f  = field[idx];
    float4 sg = signal[idx];

    float a0 = is / (1.0f + __expf(-(gr + c0)));
    float a1 = is / (1.0f + __expf(-(gr + c1)));
    float a2 = is / (1.0f + __expf(-(gr + c2)));
    float a3 = is / (1.0f + __expf(-(gr + c3)));

    float ux = f.x + (sg.x - f.x) * a0;
    float uy = f.y + (sg.y - f.y) * a1;
    float uz = f.z + (sg.z - f.z) * a2;
    float uw = f.w + (sg.w - f.w) * a3;

    float sf = f.x * f.x + f.y * f.y + f.z * f.z + f.w * f.w;
    float su = ux * ux + uy * uy + uz * uz + uw * uw;
#pragma unroll
    for (int off = 32; off > 0; off >>= 1) {
        sf += __shfl_down(sf, off, 64);
        su += __shfl_down(su, off, 64);
    }
    const int wave = t >> 6;
    if ((t & 63) == 0) {
        s_part[0][wave] = sf;
        s_part[1][wave] = su;
    }
    __syncthreads();
    if (t == 0) {
        part[row] = make_float2(
            s_part[0][0] + s_part[0][1] + s_part[0][2] + s_part[0][3],
            s_part[1][0] + s_part[1][1] + s_part[1][2] + s_part[1][3]);
    }
}

// ------- Kernel 2: reduce partials -> scale; recompute u; write out --------
__global__ __launch_bounds__(256) void frp_write(
    const float4* __restrict__ field,
    const float4* __restrict__ signal,
    const int*   __restrict__ apos,
    const float* __restrict__ astr,
    const float* __restrict__ p_is,
    const float* __restrict__ p_gr,
    const float* __restrict__ p_lr,
    const float2* __restrict__ part,
    float4* __restrict__ out)
{
    __shared__ int   s_pj[NA];
    __shared__ int   s_rad[NA];
    __shared__ int   s_di2[NA];
    __shared__ float s_coef[NA];
    __shared__ float s_inv[NA];
    __shared__ int   s_nact;
    __shared__ double s_red[2][4];
    __shared__ float s_scale;

    const float lr = *p_lr;
    const float gr = *p_gr;
    const float is = *p_is;

    const int row = blockIdx.x;
    const int t   = threadIdx.x;

    // issue partial loads early (independent of everything below)
    const float4* p4 = (const float4*)part;      // (f0,u0,f1,u1) pairs, 512 total
    float4 v0 = p4[t];
    float4 v1 = p4[t + 256];

    // issue field/signal loads early too
    const int idx = row * (WW / 4) + t;
    float4 f  = field[idx];
    float4 sg = signal[idx];

    if (t < NA) {                         // wave 0: compact row-active attractors
        float s  = astr[t];
        int   pi = apos[2 * t + 0];
        int   pj = apos[2 * t + 1];
        int   r  = (int)floorf(5.0f * s);
        int   di = row - pi;
        bool active = (di >= -r && di <= r);
        unsigned long long mask = __ballot(active);
        int pos = __popcll(mask & ((1ull << t) - 1ull));
        if (active) {
            s_pj[pos]   = pj;
            s_rad[pos]  = r;
            s_di2[pos]  = di * di;
            s_coef[pos] = lr * s;
            s_inv[pos]  = -0.125f / (s * s);
        }
        if (t == 0) s_nact = __popcll(mask);
    }

    // reduce the 1024 float2 partials -> scale
    double df = (double)v0.x + (double)v0.z + (double)v1.x + (double)v1.z;
    double du = (double)v0.y + (double)v0.w + (double)v1.y + (double)v1.w;
#pragma unroll
    for (int off = 32; off > 0; off >>= 1) {
        df += __shfl_down(df, off, 64);
        du += __shfl_down(du, off, 64);
    }
    const int wave = t >> 6;
    if ((t & 63) == 0) { s_red[0][wave] = df; s_red[1][wave] = du; }
    __syncthreads();
    if (t == 0) {
        double tf = s_red[0][0] + s_red[0][1] + s_red[0][2] + s_red[0][3];
        double tu = s_red[1][0] + s_red[1][1] + s_red[1][2] + s_red[1][3];
        s_scale = (tu > 0.0) ? (float)sqrt(tf / tu) : 1.0f;
    }
    __syncthreads();

    // recompute u (identical formula to k1) and write scaled
    const int col0 = t << 2;
    const int n    = s_nact;

    float c0 = 0.f, c1 = 0.f, c2 = 0.f, c3 = 0.f;
    for (int k = 0; k < n; ++k) {
        int   pj  = s_pj[k];
        int   r   = s_rad[k];
        int   di2 = s_di2[k];
        float cf  = s_coef[k];
        float iv  = s_inv[k];
        int dj = col0 - pj;
        if (dj >= -r && dj <= r) c0 += cf * __expf(iv * (float)(di2 + dj * dj));
        int d1 = dj + 1;
        if (d1 >= -r && d1 <= r) c1 += cf * __expf(iv * (float)(di2 + d1 * d1));
        int d2 = dj + 2;
        if (d2 >= -r && d2 <= r) c2 += cf * __expf(iv * (float)(di2 + d2 * d2));
        int d3 = dj + 3;
        if (d3 >= -r && d3 <= r) c3 += cf * __expf(iv * (float)(di2 + d3 * d3));
    }

    float a0 = is / (1.0f + __expf(-(gr + c0)));
    float a1 = is / (1.0f + __expf(-(gr + c1)));
    float a2 = is / (1.0f + __expf(-(gr + c2)));
    float a3 = is / (1.0f + __expf(-(gr + c3)));

    const float sc = s_scale;
    float4 u;
    u.x = (f.x + (sg.x - f.x) * a0) * sc;
    u.y = (f.y + (sg.y - f.y) * a1) * sc;
    u.z = (f.z + (sg.z - f.z) * a2) * sc;
    u.w = (f.w + (sg.w - f.w) * a3) * sc;
    out[idx] = u;
}

extern "C" void kernel_launch(void* const* d_in, const int* in_sizes, int n_in,
                              void* d_out, int out_size, void* d_ws, size_t ws_size,
                              hipStream_t stream) {
    const float4* field  = (const float4*)d_in[0];
    const float4* signal = (const float4*)d_in[1];
    const int*    apos   = (const int*)d_in[2];
    const float*  astr   = (const float*)d_in[3];
    const float*  p_is   = (const float*)d_in[4];
    const float*  p_gr   = (const float*)d_in[5];
    const float*  p_lr   = (const float*)d_in[6];

    float2* part = (float2*)d_ws;

    frp_norm<<<NBLK, 256, 0, stream>>>(
        field, signal, apos, astr, p_is, p_gr, p_lr, part);

    frp_write<<<NBLK, 256, 0, stream>>>(
        field, signal, apos, astr, p_is, p_gr, p_lr, part, (float4*)d_out);
}